// Round 7
// baseline (68.711 us; speedup 1.0000x reference)
//
#include <hip/hip_runtime.h>
#include <hip/hip_bf16.h>

#define BB 128      // batch
#define SS 128      // seq len
#define VD 128      // VALUE_DIM
#define CN 64       // CONCEPT_NUM
#define KD 128      // KEY_DIM
#define QN 10000
#define MROWS (2*BB*SS)       // 32768
#define MTOT  (MROWS + BB)    // 32896

typedef __attribute__((ext_vector_type(8))) short bf16x8;
typedef __attribute__((ext_vector_type(4))) float f32x4;

__device__ __forceinline__ float bflo(unsigned int u) { return __uint_as_float(u << 16); }
__device__ __forceinline__ unsigned short f2bf(float f) {
    unsigned int x = __float_as_uint(f);
    return (unsigned short)((x + 0x7fffu + ((x >> 16) & 1u)) >> 16);
}
__device__ __forceinline__ unsigned int pk2(float lo, float hi) {
    return (unsigned int)f2bf(lo) | ((unsigned int)f2bf(hi) << 16);
}
__device__ __forceinline__ float fast_tanh(float x) {
    float e = __expf(2.0f * x);
    return 1.0f - 2.0f / (e + 1.0f);
}
__device__ __forceinline__ float fast_sig(float x) {
    return 1.0f / (1.0f + __expf(-x));
}

// ---------------- kernel 1: weight pack (blocks 0..19) + counts (block 20) ----------------
__global__ __launch_bounds__(256) void k_wcnt(
    const float* __restrict__ erase_W, const float* __restrict__ add_W,
    const float* __restrict__ key_W, unsigned short* __restrict__ Bfrag,
    const int* __restrict__ ri, const int* __restrict__ wi, float* __restrict__ sig)
{
    if (blockIdx.x < 20) {
        const int bid = blockIdx.x * 4 + (threadIdx.x >> 6);   // 0..79
        const int l = threadIdx.x & 63;
        const int n = (bid >> 2) * 16 + (l & 15);
        const int k0 = (bid & 3) * 32 + (l >> 4) * 8;
        const float* src;
        if (n < 128)      src = erase_W + (size_t)n * KD + k0;
        else if (n < 256) src = add_W + (size_t)(n - 128) * KD + k0;
        else              src = key_W + (size_t)(n - 256) * KD + k0;
        float4 fa = ((const float4*)src)[0];
        float4 fb = ((const float4*)src)[1];
        uint4 o = make_uint4(pk2(fa.x, fa.y), pk2(fa.z, fa.w), pk2(fb.x, fb.y), pk2(fb.z, fb.w));
        *(uint4*)(Bfrag + ((size_t)bid * 64 + l) * 8) = o;
    } else {
        __shared__ int sr_s[4], sw_s[4];
        const int t = threadIdx.x;
        const int4* r4 = (const int4*)ri;
        const int4* w4 = (const int4*)wi;
        int sr = 0, sw = 0;
        #pragma unroll 4
        for (int p = 0; p < 16; ++p) {
            int4 a = r4[p * 256 + t];
            int4 b = w4[p * 256 + t];
            sr += (a.x >= 1) + (a.y >= 1) + (a.z >= 1) + (a.w >= 1);
            sw += (b.x >= 1) + (b.y >= 1) + (b.z >= 1) + (b.w >= 1);
        }
        for (int off = 1; off < 64; off <<= 1) { sr += __shfl_xor(sr, off); sw += __shfl_xor(sw, off); }
        int wid = t >> 6;
        if ((t & 63) == 0) { sr_s[wid] = sr; sw_s[wid] = sw; }
        __syncthreads();
        if (t == 0) {
            int SR = sr_s[0]+sr_s[1]+sr_s[2]+sr_s[3];
            int SW = sw_s[0]+sw_s[1]+sw_s[2]+sw_s[3];
            sig[0] = 1.0f / (1.0f + __expf(-(float)SR));
            sig[1] = 1.0f / (1.0f + __expf(-(float)SW));
        }
    }
}

// ---------------- kernel 2: MFMA precompute -> Ef/Af (f32 planes, [row][v]) + Wf/WT (f32) ----------------
__global__ __launch_bounds__(256) void k_mfma(
    const int* __restrict__ ri, const int* __restrict__ wi, const int* __restrict__ tgt,
    const float* __restrict__ q_emb, const float* __restrict__ i_emb,
    const float* __restrict__ erase_b, const float* __restrict__ add_b,
    const unsigned short* __restrict__ Bfrag,
    float* __restrict__ Ef, float* __restrict__ Af,
    float* __restrict__ Wf, float* __restrict__ WTbuf)
{
    __shared__ __align__(16) char shA[32 * 256];      // Xi bf16, swizzled
    __shared__ __align__(16) char shB[32 * 68 * 4];   // Xq bf16 swizzled, then logits f32 [32][68]
    __shared__ int id_s[32], ir_s[32];

    const int t = threadIdx.x;
    const int lane = t & 63;
    const int w = t >> 6;
    const int base = blockIdx.x * 32;
    const bool ea = (base < MROWS);

    if (t < 32) {
        int r = base + t;
        int irow = 0, qid;
        if (r < MROWS) {
            int m = r >> 14;
            int idx = r & 16383;
            int inter = (m == 0) ? ri[idx] : wi[idx];
            irow = inter;
            qid = (inter > QN) ? inter - QN : inter;
        } else {
            qid = tgt[r - MROWS];
        }
        id_s[t] = qid; ir_s[t] = irow;
    }
    __syncthreads();

    // stage Xq (always) and Xi (if E/A block), bf16 + XOR-swizzle (byte ^= (row&7)<<4)
    {
        const int r = t >> 3, o = t & 7;
        const int bb = r * 256 + o * 32;
        const int sw = (r & 7) << 4;
        {
            const float* src = q_emb + (size_t)id_s[r] * KD + o * 16;
            float4 f0 = ((const float4*)src)[0];
            float4 f1 = ((const float4*)src)[1];
            float4 f2 = ((const float4*)src)[2];
            float4 f3 = ((const float4*)src)[3];
            *(uint4*)(shB + (bb ^ sw))        = make_uint4(pk2(f0.x,f0.y), pk2(f0.z,f0.w), pk2(f1.x,f1.y), pk2(f1.z,f1.w));
            *(uint4*)(shB + ((bb + 16) ^ sw)) = make_uint4(pk2(f2.x,f2.y), pk2(f2.z,f2.w), pk2(f3.x,f3.y), pk2(f3.z,f3.w));
        }
        if (ea) {
            const float* src = i_emb + (size_t)ir_s[r] * KD + o * 16;
            float4 f0 = ((const float4*)src)[0];
            float4 f1 = ((const float4*)src)[1];
            float4 f2 = ((const float4*)src)[2];
            float4 f3 = ((const float4*)src)[3];
            *(uint4*)(shA + (bb ^ sw))        = make_uint4(pk2(f0.x,f0.y), pk2(f0.z,f0.w), pk2(f1.x,f1.y), pk2(f1.z,f1.w));
            *(uint4*)(shA + ((bb + 16) ^ sw)) = make_uint4(pk2(f2.x,f2.y), pk2(f2.z,f2.w), pk2(f3.x,f3.y), pk2(f3.z,f3.w));
        }
    }
    __syncthreads();

    // ---- key logits GEMM: Xq(32x128) x key_W^T(128x64), wave w owns cols w*16..w*16+15 ----
    const int rowl = lane & 15;
    const int kb16 = (lane >> 4) * 16;

    bf16x8 afQ[2][4];
    #pragma unroll
    for (int mt = 0; mt < 2; ++mt)
        #pragma unroll
        for (int kt = 0; kt < 4; ++kt) {
            int row = mt * 16 + rowl;
            int addr = (row * 256 + kt * 64 + kb16) ^ ((row & 7) << 4);
            afQ[mt][kt] = *(const bf16x8*)(shB + addr);
        }

    f32x4 accK0 = {0.f,0.f,0.f,0.f}, accK1 = {0.f,0.f,0.f,0.f};
    {
        const int gk = 16 + w;
        #pragma unroll
        for (int kt = 0; kt < 4; ++kt) {
            bf16x8 bf = *(const bf16x8*)(Bfrag + ((size_t)(gk * 4 + kt) * 64 + lane) * 8);
            accK0 = __builtin_amdgcn_mfma_f32_16x16x32_bf16(afQ[0][kt], bf, accK0, 0, 0, 0);
            accK1 = __builtin_amdgcn_mfma_f32_16x16x32_bf16(afQ[1][kt], bf, accK1, 0, 0, 0);
        }
    }
    __syncthreads();   // done reading shB (Xq)

    // write logits to shB as f32 [32][68]
    {
        float* L = (float*)shB;
        const int col = w * 16 + rowl;
        const int rb4 = (lane >> 4) * 4;
        #pragma unroll
        for (int rr = 0; rr < 4; ++rr) L[(rb4 + rr) * 68 + col] = accK0[rr];
        #pragma unroll
        for (int rr = 0; rr < 4; ++rr) L[(16 + rb4 + rr) * 68 + col] = accK1[rr];
    }
    __syncthreads();

    // softmax over 64 cols: 8 threads per row, shfl-reduce in 8-lane groups
    {
        const float* L = (const float*)shB;
        const int rr = t >> 3, q = t & 7;
        float4 va = *(const float4*)(L + rr * 68 + q * 8);
        float4 vb = *(const float4*)(L + rr * 68 + q * 8 + 4);
        float mx = fmaxf(fmaxf(fmaxf(va.x, va.y), fmaxf(va.z, va.w)),
                         fmaxf(fmaxf(vb.x, vb.y), fmaxf(vb.z, vb.w)));
        #pragma unroll
        for (int off = 1; off < 8; off <<= 1) mx = fmaxf(mx, __shfl_xor(mx, off));
        float e0 = __expf(va.x - mx), e1 = __expf(va.y - mx), e2 = __expf(va.z - mx), e3 = __expf(va.w - mx);
        float e4 = __expf(vb.x - mx), e5 = __expf(vb.y - mx), e6 = __expf(vb.z - mx), e7 = __expf(vb.w - mx);
        float s = e0 + e1 + e2 + e3 + e4 + e5 + e6 + e7;
        #pragma unroll
        for (int off = 1; off < 8; off <<= 1) s += __shfl_xor(s, off);
        float inv = 1.0f / s;
        int R = base + rr;
        if (R < MROWS) {
            float* dw = Wf + (size_t)R * CN + q * 8;
            *(float4*)dw       = make_float4(e0*inv, e1*inv, e2*inv, e3*inv);
            *(float4*)(dw + 4) = make_float4(e4*inv, e5*inv, e6*inv, e7*inv);
        } else {
            float* dst = WTbuf + (size_t)(R - MROWS) * CN + q * 8;
            *(float4*)dst       = make_float4(e0*inv, e1*inv, e2*inv, e3*inv);
            *(float4*)(dst + 4) = make_float4(e4*inv, e5*inv, e6*inv, e7*inv);
        }
    }

    // ---- E/A GEMM: Xi(32x128) x [erase;add]^T(128x256); wave w owns g = w, w+4, w+8, w+12 ----
    // Epilogue writes f32 planes Ef[row][v], Af[row][v].
    if (ea) {
        bf16x8 afI[2][4];
        #pragma unroll
        for (int mt = 0; mt < 2; ++mt)
            #pragma unroll
            for (int kt = 0; kt < 4; ++kt) {
                int row = mt * 16 + rowl;
                int addr = (row * 256 + kt * 64 + kb16) ^ ((row & 7) << 4);
                afI[mt][kt] = *(const bf16x8*)(shA + addr);
            }

        const int rb4 = (lane >> 4) * 4;
        f32x4 accE[2][2], accA[2][2];   // [ci][mt]
        #pragma unroll
        for (int gi = 0; gi < 4; ++gi) {
            const int g = w + gi * 4;            // 0..15
            f32x4 a0 = {0.f,0.f,0.f,0.f}, a1 = {0.f,0.f,0.f,0.f};
            #pragma unroll
            for (int kt = 0; kt < 4; ++kt) {
                bf16x8 bf = *(const bf16x8*)(Bfrag + ((size_t)(g * 4 + kt) * 64 + lane) * 8);
                a0 = __builtin_amdgcn_mfma_f32_16x16x32_bf16(afI[0][kt], bf, a0, 0, 0, 0);
                a1 = __builtin_amdgcn_mfma_f32_16x16x32_bf16(afI[1][kt], bf, a1, 0, 0, 0);
            }
            if (gi < 2) { accE[gi][0] = a0; accE[gi][1] = a1; }
            else        { accA[gi - 2][0] = a0; accA[gi - 2][1] = a1; }
        }
        #pragma unroll
        for (int ci = 0; ci < 2; ++ci) {
            const int cc = ci * 64 + w * 16 + rowl;   // col within V (0..127)
            const float bvE = erase_b[cc];
            const float bvA = add_b[cc];
            #pragma unroll
            for (int mt = 0; mt < 2; ++mt) {
                #pragma unroll
                for (int rr = 0; rr < 4; ++rr) {
                    const size_t idx = (size_t)(base + mt * 16 + rb4 + rr) * VD + cc;
                    Ef[idx] = fast_sig(accE[ci][mt][rr] + bvE);
                    Af[idx] = fast_tanh(accA[ci][mt][rr] + bvA);
                }
            }
        }
    }
}

// ---------------- kernel 3: scan; lane = concept, W per-lane LDS b32, E/A uniform f32 loads ----------------
// grid 256 (chain), block 1024 = 16 waves; wave wv owns v = wv*8 .. wv*8+7, lane = c.
__global__ __launch_bounds__(1024, 2) void k_scan(
    const float* __restrict__ Ef, const float* __restrict__ Af,
    const float* __restrict__ Wf, const float* __restrict__ WTbuf,
    const float* __restrict__ rmem0, const float* __restrict__ wmem0,
    float* __restrict__ readbuf)
{
    __shared__ float lds_w[SS * CN];   // 32 KB
    const int t = threadIdx.x;
    const int chain = blockIdx.x;      // m*BB + b
    const int m = chain >> 7;
    const int b = chain & 127;
    const int lane = t & 63;           // concept c
    const int wv = __builtin_amdgcn_readfirstlane(t >> 6);   // 0..15, wave-uniform SGPR
    const int v0 = wv * 8;

    // stage W [128][64] f32, fully coalesced
    {
        const float4* src = (const float4*)(Wf + (size_t)chain * SS * CN);
        float4* dst = (float4*)lds_w;
        dst[t] = src[t];
        dst[t + 1024] = src[t + 1024];
    }

    // init state: mm[j] = minit[v0+j][lane]
    const float* minit = (m == 0) ? rmem0 : wmem0;
    float mm[8];
    #pragma unroll
    for (int j = 0; j < 8; ++j) mm[j] = minit[(v0 + j) * CN + lane];

    const float* ep = Ef + (size_t)chain * SS * VD + v0;   // lane-invariant
    const float* ap = Af + (size_t)chain * SS * VD + v0;
    __syncthreads();

    for (int so = 0; so < 16; ++so) {
        #pragma unroll
        for (int k = 0; k < 8; ++k) {
            const int s = so * 8 + k;
            float w_c = lds_w[s * CN + lane];               // ds_read_b32, conflict-free
            const float* e8 = ep + (size_t)s * VD;
            const float* a8 = ap + (size_t)s * VD;
            float4 e03 = *(const float4*)e8;                // uniform 16B loads
            float4 e47 = *(const float4*)(e8 + 4);
            float4 a03 = *(const float4*)a8;
            float4 a47 = *(const float4*)(a8 + 4);
            const float ev[8] = { e03.x, e03.y, e03.z, e03.w, e47.x, e47.y, e47.z, e47.w };
            const float av[8] = { a03.x, a03.y, a03.z, a03.w, a47.x, a47.y, a47.z, a47.w };
            #pragma unroll
            for (int j = 0; j < 8; ++j) {
                float d = fmaf(-ev[j], w_c, 1.0f);          // 1 - e*w
                float u = av[j] * w_c;                      // a*w
                mm[j] = fmaf(mm[j], d, u);                  // m*d + u
            }
        }
    }

    // read: out[v0+j] = sum_c mm[j] * WT[b][c]
    const float wtv = WTbuf[(size_t)b * CN + lane];
    #pragma unroll
    for (int j = 0; j < 8; ++j) {
        float p = mm[j] * wtv;
        #pragma unroll
        for (int off = 1; off < 64; off <<= 1) p += __shfl_xor(p, off);
        if (lane == j) readbuf[(size_t)chain * VD + v0 + j] = p;
    }
}

// ---------------- kernel 4: head (256 threads, k-split) ----------------
__global__ __launch_bounds__(256) void k_head(
    const float* __restrict__ readbuf, const int* __restrict__ tgt,
    const float* __restrict__ q_emb,
    const float* __restrict__ rsum_W, const float* __restrict__ rsum_b,
    const float* __restrict__ wsum_W, const float* __restrict__ wsum_b,
    const float* __restrict__ succ_W, const float* __restrict__ succ_b,
    const float* __restrict__ fail_W, const float* __restrict__ fail_b,
    const float* __restrict__ diff_W, const float* __restrict__ diff_b,
    const float* __restrict__ sig, float* __restrict__ out)
{
    __shared__ float xr[256], xw[256];
    __shared__ float part[2][128];
    __shared__ float red_s[6];
    const int t = threadIdx.x;
    const int j = t & 127;
    const int h = t >> 7;
    const int b = blockIdx.x;
    if (h == 0) {
        int tid_ = tgt[b];
        float qv = q_emb[(size_t)tid_ * KD + j];
        xr[j]       = readbuf[(size_t)b * VD + j];
        xr[128 + j] = qv;
        xw[j]       = readbuf[(size_t)(BB + b) * VD + j];
        xw[128 + j] = qv;
    }
    __syncthreads();

    float rs = (h == 0) ? rsum_b[j] : 0.0f;
    float wv = (h == 0) ? wsum_b[j] : 0.0f;
    const float* rw = rsum_W + (size_t)j * 256 + h * 128;
    const float* ww = wsum_W + (size_t)j * 256 + h * 128;
    const float* xrp = xr + h * 128;
    const float* xwp = xw + h * 128;
    #pragma unroll 4
    for (int k = 0; k < 128; ++k) {
        rs = fmaf(rw[k], xrp[k], rs);
        wv = fmaf(ww[k], xwp[k], wv);
    }
    if (h == 1) { part[0][j] = rs; part[1][j] = wv; }
    __syncthreads();
    if (h == 0) {
        rs += part[0][j];
        wv += part[1][j];
        float r_sum = fast_tanh(rs), w_sum = fast_tanh(wv);
        float qv = xr[128 + j];
        float ps = r_sum * succ_W[j];
        float pf = w_sum * fail_W[j];
        float pd = qv    * diff_W[j];
        for (int off = 1; off < 64; off <<= 1) {
            ps += __shfl_xor(ps, off);
            pf += __shfl_xor(pf, off);
            pd += __shfl_xor(pd, off);
        }
        int wid = j >> 6;
        if ((j & 63) == 0) { red_s[wid*3+0] = ps; red_s[wid*3+1] = pf; red_s[wid*3+2] = pd; }
    }
    __syncthreads();
    if (t == 0) {
        float Ps = red_s[0] + red_s[3];
        float Pf = red_s[1] + red_s[4];
        float Pd = red_s[2] + red_s[5];
        float succ = fast_tanh(Ps + succ_b[0]);
        float fail = fast_tanh(Pf + fail_b[0]);
        float diff = fast_tanh(Pd + diff_b[0]);
        out[b] = succ * sig[0] + fail * sig[1] - 2.0f * diff;
    }
}

extern "C" void kernel_launch(void* const* d_in, const int* in_sizes, int n_in,
                              void* d_out, int out_size, void* d_ws, size_t ws_size,
                              hipStream_t stream) {
    const int*   ri      = (const int*)d_in[0];
    const int*   wi      = (const int*)d_in[1];
    const int*   tgt     = (const int*)d_in[2];
    const float* q_emb   = (const float*)d_in[3];
    const float* i_emb   = (const float*)d_in[4];
    const float* key_W   = (const float*)d_in[5];
    const float* erase_W = (const float*)d_in[6];
    const float* erase_b = (const float*)d_in[7];
    const float* add_W   = (const float*)d_in[8];
    const float* add_b   = (const float*)d_in[9];
    const float* rsum_W  = (const float*)d_in[10];
    const float* rsum_b  = (const float*)d_in[11];
    const float* wsum_W  = (const float*)d_in[12];
    const float* wsum_b  = (const float*)d_in[13];
    const float* succ_W  = (const float*)d_in[14];
    const float* succ_b  = (const float*)d_in[15];
    const float* fail_W  = (const float*)d_in[16];
    const float* fail_b  = (const float*)d_in[17];
    const float* diff_W  = (const float*)d_in[18];
    const float* diff_b  = (const float*)d_in[19];
    const float* rmem0   = (const float*)d_in[20];
    const float* wmem0   = (const float*)d_in[21];

    char* ws = (char*)d_ws;
    float*          Ef      = (float*)(ws + 0);                   // 16,777,216 B
    float*          Af      = (float*)(ws + 16777216);            // 16,777,216 B
    float*          Wf      = (float*)(ws + 33554432);            //  8,388,608 B
    float*          WTbuf   = (float*)(ws + 41943040);            //     32,768 B
    float*          readbuf = (float*)(ws + 41975808);            //    131,072 B
    unsigned short* Bfrag   = (unsigned short*)(ws + 42106880);   //     81,920 B
    float*          sig     = (float*)(ws + 42188800);            //          8 B
    float*          out     = (float*)d_out;

    hipLaunchKernelGGL(k_wcnt, dim3(21), dim3(256), 0, stream,
        erase_W, add_W, key_W, Bfrag, ri, wi, sig);
    hipLaunchKernelGGL(k_mfma, dim3(1028), dim3(256), 0, stream,
        ri, wi, tgt, q_emb, i_emb, erase_b, add_b, Bfrag,
        Ef, Af, Wf, WTbuf);
    hipLaunchKernelGGL(k_scan, dim3(256), dim3(1024), 0, stream,
        Ef, Af, Wf, WTbuf, rmem0, wmem0, readbuf);
    hipLaunchKernelGGL(k_head, dim3(128), dim3(256), 0, stream,
        readbuf, tgt, q_emb, rsum_W, rsum_b, wsum_W, wsum_b,
        succ_W, succ_b, fail_W, fail_b, diff_W, diff_b, sig, out);
}

// Round 8
// 57.858 us; speedup vs baseline: 1.1876x; 1.1876x over previous
//
#include <hip/hip_runtime.h>
#include <hip/hip_bf16.h>

#define BB 128      // batch
#define SS 128      // seq len
#define VD 128      // VALUE_DIM
#define CN 64       // CONCEPT_NUM
#define KD 128      // KEY_DIM
#define QN 10000
#define MROWS (2*BB*SS)       // 32768
#define MTOT  (MROWS + BB)    // 32896

typedef __attribute__((ext_vector_type(8))) short bf16x8;
typedef __attribute__((ext_vector_type(4))) float f32x4;

__device__ __forceinline__ float bflo(unsigned int u) { return __uint_as_float(u << 16); }
__device__ __forceinline__ float bfhi(unsigned int u) { return __uint_as_float(u & 0xffff0000u); }
__device__ __forceinline__ unsigned short f2bf(float f) {
    unsigned int x = __float_as_uint(f);
    return (unsigned short)((x + 0x7fffu + ((x >> 16) & 1u)) >> 16);
}
__device__ __forceinline__ unsigned int pk2(float lo, float hi) {
    return (unsigned int)f2bf(lo) | ((unsigned int)f2bf(hi) << 16);
}
__device__ __forceinline__ float fast_tanh(float x) {
    float e = __expf(2.0f * x);
    return 1.0f - 2.0f / (e + 1.0f);
}
__device__ __forceinline__ float fast_sig(float x) {
    return 1.0f / (1.0f + __expf(-x));
}

// ---------------- kernel 1: weight pack (blocks 0..19) + counts (block 20) ----------------
__global__ __launch_bounds__(256) void k_wcnt(
    const float* __restrict__ erase_W, const float* __restrict__ add_W,
    const float* __restrict__ key_W, unsigned short* __restrict__ Bfrag,
    const int* __restrict__ ri, const int* __restrict__ wi, float* __restrict__ sig)
{
    if (blockIdx.x < 20) {
        const int bid = blockIdx.x * 4 + (threadIdx.x >> 6);   // 0..79
        const int l = threadIdx.x & 63;
        const int n = (bid >> 2) * 16 + (l & 15);
        const int k0 = (bid & 3) * 32 + (l >> 4) * 8;
        const float* src;
        if (n < 128)      src = erase_W + (size_t)n * KD + k0;
        else if (n < 256) src = add_W + (size_t)(n - 128) * KD + k0;
        else              src = key_W + (size_t)(n - 256) * KD + k0;
        float4 fa = ((const float4*)src)[0];
        float4 fb = ((const float4*)src)[1];
        uint4 o = make_uint4(pk2(fa.x, fa.y), pk2(fa.z, fa.w), pk2(fb.x, fb.y), pk2(fb.z, fb.w));
        *(uint4*)(Bfrag + ((size_t)bid * 64 + l) * 8) = o;
    } else {
        __shared__ int sr_s[4], sw_s[4];
        const int t = threadIdx.x;
        const int4* r4 = (const int4*)ri;
        const int4* w4 = (const int4*)wi;
        int sr = 0, sw = 0;
        #pragma unroll 4
        for (int p = 0; p < 16; ++p) {
            int4 a = r4[p * 256 + t];
            int4 b = w4[p * 256 + t];
            sr += (a.x >= 1) + (a.y >= 1) + (a.z >= 1) + (a.w >= 1);
            sw += (b.x >= 1) + (b.y >= 1) + (b.z >= 1) + (b.w >= 1);
        }
        for (int off = 1; off < 64; off <<= 1) { sr += __shfl_xor(sr, off); sw += __shfl_xor(sw, off); }
        int wid = t >> 6;
        if ((t & 63) == 0) { sr_s[wid] = sr; sw_s[wid] = sw; }
        __syncthreads();
        if (t == 0) {
            int SR = sr_s[0]+sr_s[1]+sr_s[2]+sr_s[3];
            int SW = sw_s[0]+sw_s[1]+sw_s[2]+sw_s[3];
            sig[0] = 1.0f / (1.0f + __expf(-(float)SR));
            sig[1] = 1.0f / (1.0f + __expf(-(float)SW));
        }
    }
}

// ---------------- kernel 2: MFMA precompute -> EA (packed u32 {e,a}) + Wbf (bf16) / WT (f32) ----------------
__global__ __launch_bounds__(256) void k_mfma(
    const int* __restrict__ ri, const int* __restrict__ wi, const int* __restrict__ tgt,
    const float* __restrict__ q_emb, const float* __restrict__ i_emb,
    const float* __restrict__ erase_b, const float* __restrict__ add_b,
    const unsigned short* __restrict__ Bfrag,
    unsigned int* __restrict__ EAbuf,
    unsigned short* __restrict__ Wbf, float* __restrict__ WTbuf)
{
    __shared__ __align__(16) char shA[32 * 256];      // Xi bf16, swizzled
    __shared__ __align__(16) char shB[32 * 68 * 4];   // Xq bf16 swizzled, then logits f32 [32][68]
    __shared__ int id_s[32], ir_s[32];

    const int t = threadIdx.x;
    const int lane = t & 63;
    const int w = t >> 6;
    const int base = blockIdx.x * 32;
    const bool ea = (base < MROWS);

    if (t < 32) {
        int r = base + t;
        int irow = 0, qid;
        if (r < MROWS) {
            int m = r >> 14;
            int idx = r & 16383;
            int inter = (m == 0) ? ri[idx] : wi[idx];
            irow = inter;
            qid = (inter > QN) ? inter - QN : inter;
        } else {
            qid = tgt[r - MROWS];
        }
        id_s[t] = qid; ir_s[t] = irow;
    }
    __syncthreads();

    // stage Xq (always) and Xi (if E/A block), bf16 + XOR-swizzle (byte ^= (row&7)<<4)
    {
        const int r = t >> 3, o = t & 7;
        const int bb = r * 256 + o * 32;
        const int sw = (r & 7) << 4;
        {
            const float* src = q_emb + (size_t)id_s[r] * KD + o * 16;
            float4 f0 = ((const float4*)src)[0];
            float4 f1 = ((const float4*)src)[1];
            float4 f2 = ((const float4*)src)[2];
            float4 f3 = ((const float4*)src)[3];
            *(uint4*)(shB + (bb ^ sw))        = make_uint4(pk2(f0.x,f0.y), pk2(f0.z,f0.w), pk2(f1.x,f1.y), pk2(f1.z,f1.w));
            *(uint4*)(shB + ((bb + 16) ^ sw)) = make_uint4(pk2(f2.x,f2.y), pk2(f2.z,f2.w), pk2(f3.x,f3.y), pk2(f3.z,f3.w));
        }
        if (ea) {
            const float* src = i_emb + (size_t)ir_s[r] * KD + o * 16;
            float4 f0 = ((const float4*)src)[0];
            float4 f1 = ((const float4*)src)[1];
            float4 f2 = ((const float4*)src)[2];
            float4 f3 = ((const float4*)src)[3];
            *(uint4*)(shA + (bb ^ sw))        = make_uint4(pk2(f0.x,f0.y), pk2(f0.z,f0.w), pk2(f1.x,f1.y), pk2(f1.z,f1.w));
            *(uint4*)(shA + ((bb + 16) ^ sw)) = make_uint4(pk2(f2.x,f2.y), pk2(f2.z,f2.w), pk2(f3.x,f3.y), pk2(f3.z,f3.w));
        }
    }
    __syncthreads();

    // ---- key logits GEMM: Xq(32x128) x key_W^T(128x64), wave w owns cols w*16..w*16+15 ----
    const int rowl = lane & 15;
    const int kb16 = (lane >> 4) * 16;

    bf16x8 afQ[2][4];
    #pragma unroll
    for (int mt = 0; mt < 2; ++mt)
        #pragma unroll
        for (int kt = 0; kt < 4; ++kt) {
            int row = mt * 16 + rowl;
            int addr = (row * 256 + kt * 64 + kb16) ^ ((row & 7) << 4);
            afQ[mt][kt] = *(const bf16x8*)(shB + addr);
        }

    f32x4 accK0 = {0.f,0.f,0.f,0.f}, accK1 = {0.f,0.f,0.f,0.f};
    {
        const int gk = 16 + w;
        #pragma unroll
        for (int kt = 0; kt < 4; ++kt) {
            bf16x8 bf = *(const bf16x8*)(Bfrag + ((size_t)(gk * 4 + kt) * 64 + lane) * 8);
            accK0 = __builtin_amdgcn_mfma_f32_16x16x32_bf16(afQ[0][kt], bf, accK0, 0, 0, 0);
            accK1 = __builtin_amdgcn_mfma_f32_16x16x32_bf16(afQ[1][kt], bf, accK1, 0, 0, 0);
        }
    }
    __syncthreads();   // done reading shB (Xq)

    // write logits to shB as f32 [32][68]
    {
        float* L = (float*)shB;
        const int col = w * 16 + rowl;
        const int rb4 = (lane >> 4) * 4;
        #pragma unroll
        for (int rr = 0; rr < 4; ++rr) L[(rb4 + rr) * 68 + col] = accK0[rr];
        #pragma unroll
        for (int rr = 0; rr < 4; ++rr) L[(16 + rb4 + rr) * 68 + col] = accK1[rr];
    }
    __syncthreads();

    // softmax over 64 cols: 8 threads per row, shfl-reduce in 8-lane groups
    {
        const float* L = (const float*)shB;
        const int rr = t >> 3, q = t & 7;
        float4 va = *(const float4*)(L + rr * 68 + q * 8);
        float4 vb = *(const float4*)(L + rr * 68 + q * 8 + 4);
        float mx = fmaxf(fmaxf(fmaxf(va.x, va.y), fmaxf(va.z, va.w)),
                         fmaxf(fmaxf(vb.x, vb.y), fmaxf(vb.z, vb.w)));
        #pragma unroll
        for (int off = 1; off < 8; off <<= 1) mx = fmaxf(mx, __shfl_xor(mx, off));
        float e0 = __expf(va.x - mx), e1 = __expf(va.y - mx), e2 = __expf(va.z - mx), e3 = __expf(va.w - mx);
        float e4 = __expf(vb.x - mx), e5 = __expf(vb.y - mx), e6 = __expf(vb.z - mx), e7 = __expf(vb.w - mx);
        float s = e0 + e1 + e2 + e3 + e4 + e5 + e6 + e7;
        #pragma unroll
        for (int off = 1; off < 8; off <<= 1) s += __shfl_xor(s, off);
        float inv = 1.0f / s;
        int R = base + rr;
        if (R < MROWS) {
            uint4 o = make_uint4(pk2(e0*inv, e1*inv), pk2(e2*inv, e3*inv),
                                 pk2(e4*inv, e5*inv), pk2(e6*inv, e7*inv));
            *(uint4*)(Wbf + (size_t)R * CN + q * 8) = o;
        } else {
            float* dst = WTbuf + (size_t)(R - MROWS) * CN + q * 8;
            *(float4*)dst       = make_float4(e0*inv, e1*inv, e2*inv, e3*inv);
            *(float4*)(dst + 4) = make_float4(e4*inv, e5*inv, e6*inv, e7*inv);
        }
    }

    // ---- E/A GEMM: Xi(32x128) x [erase;add]^T(128x256); wave w owns g = w, w+4, w+8, w+12 ----
    // Buffer all 4 accumulators, then write packed {e,a} u32 dwords (coalesced).
    if (ea) {
        bf16x8 afI[2][4];
        #pragma unroll
        for (int mt = 0; mt < 2; ++mt)
            #pragma unroll
            for (int kt = 0; kt < 4; ++kt) {
                int row = mt * 16 + rowl;
                int addr = (row * 256 + kt * 64 + kb16) ^ ((row & 7) << 4);
                afI[mt][kt] = *(const bf16x8*)(shA + addr);
            }

        const int rb4 = (lane >> 4) * 4;
        f32x4 accE[2][2], accA[2][2];   // [ci][mt]
        #pragma unroll
        for (int gi = 0; gi < 4; ++gi) {
            const int g = w + gi * 4;            // 0..15
            f32x4 a0 = {0.f,0.f,0.f,0.f}, a1 = {0.f,0.f,0.f,0.f};
            #pragma unroll
            for (int kt = 0; kt < 4; ++kt) {
                bf16x8 bf = *(const bf16x8*)(Bfrag + ((size_t)(g * 4 + kt) * 64 + lane) * 8);
                a0 = __builtin_amdgcn_mfma_f32_16x16x32_bf16(afI[0][kt], bf, a0, 0, 0, 0);
                a1 = __builtin_amdgcn_mfma_f32_16x16x32_bf16(afI[1][kt], bf, a1, 0, 0, 0);
            }
            if (gi < 2) { accE[gi][0] = a0; accE[gi][1] = a1; }
            else        { accA[gi - 2][0] = a0; accA[gi - 2][1] = a1; }
        }
        #pragma unroll
        for (int ci = 0; ci < 2; ++ci) {
            const int cc = ci * 64 + w * 16 + rowl;   // col within V (0..127)
            const float bvE = erase_b[cc];
            const float bvA = add_b[cc];
            #pragma unroll
            for (int mt = 0; mt < 2; ++mt) {
                #pragma unroll
                for (int rr = 0; rr < 4; ++rr) {
                    float e = fast_sig(accE[ci][mt][rr] + bvE);
                    float a = fast_tanh(accA[ci][mt][rr] + bvA);
                    EAbuf[(size_t)(base + mt * 16 + rb4 + rr) * VD + cc] = pk2(e, a);
                }
            }
        }
    }
}

// ---------------- kernel 3: scan, 4v x 4c register tile, all-LDS inner loop ----------------
// grid 256 (chain), block 512 = 8 waves. Wave w: vhalf = w&1, cq = w>>1.
// Lane: vg = lane>>2 (16 groups), cg = lane&3. Thread: v0 = vhalf*64+vg*4, c0 = cq*16+cg*4.
__global__ __launch_bounds__(512, 2) void k_scan(
    const unsigned int* __restrict__ EAbuf, const unsigned short* __restrict__ Wbf,
    const float* __restrict__ WTbuf,
    const float* __restrict__ rmem0, const float* __restrict__ wmem0,
    float* __restrict__ readbuf)
{
    __shared__ unsigned int lds_ea[SS * VD];        // 64 KB: {e,a} bf16 pair per u32
    __shared__ unsigned short lds_w[SS * CN];       // 16 KB: W bf16
    __shared__ float psum[8 * 64];                  //  2 KB
    const int t = threadIdx.x;
    const int chain = blockIdx.x;      // m*BB + b
    const int m = chain >> 7;
    const int b = chain & 127;
    const int lane = t & 63;
    const int w = t >> 6;              // 0..7 (wave-uniform)
    const int vhalf = w & 1;
    const int cq = w >> 1;
    const int vg = lane >> 2;
    const int cg = lane & 3;
    const int v0 = vhalf * 64 + vg * 4;
    const int c0 = cq * 16 + cg * 4;

    // stage EA (64 KB) and W (16 KB), fully coalesced
    {
        const uint4* sEA = (const uint4*)(EAbuf + (size_t)chain * SS * VD);
        uint4* dEA = (uint4*)lds_ea;
        #pragma unroll
        for (int i = 0; i < 8; ++i) dEA[t + i * 512] = sEA[t + i * 512];
        const uint4* sW = (const uint4*)(Wbf + (size_t)chain * SS * CN);
        uint4* dW = (uint4*)lds_w;
        dW[t] = sW[t];
        dW[t + 512] = sW[t + 512];
    }

    // init state mm[j][k] = minit[v0+j][c0+k]
    const float* minit = (m == 0) ? rmem0 : wmem0;
    float mm[4][4];
    #pragma unroll
    for (int j = 0; j < 4; ++j) {
        float4 mi = *(const float4*)(minit + (v0 + j) * CN + c0);
        mm[j][0] = mi.x; mm[j][1] = mi.y; mm[j][2] = mi.z; mm[j][3] = mi.w;
    }
    __syncthreads();

    for (int so = 0; so < 32; ++so) {
        #pragma unroll
        for (int kk = 0; kk < 4; ++kk) {
            const int s = so * 4 + kk;
            uint4 ea = *(const uint4*)(lds_ea + s * VD + v0);         // ds_read_b128
            uint2 wu = *(const uint2*)(lds_w + s * CN + c0);          // ds_read_b64
            float e[4] = { bflo(ea.x), bflo(ea.y), bflo(ea.z), bflo(ea.w) };
            float a[4] = { bfhi(ea.x), bfhi(ea.y), bfhi(ea.z), bfhi(ea.w) };
            float wv[4] = { bflo(wu.x), bfhi(wu.x), bflo(wu.y), bfhi(wu.y) };
            #pragma unroll
            for (int j = 0; j < 4; ++j) {
                #pragma unroll
                for (int k = 0; k < 4; ++k) {
                    float g = fmaf(-e[j], mm[j][k], a[j]);   // a - e*m
                    mm[j][k] = fmaf(wv[k], g, mm[j][k]);     // m + w*(a - e*m)
                }
            }
        }
    }

    // read: p[j] = sum_k mm[j][k] * WT[b][c0+k]; reduce over cg (lanes) then cq (waves)
    float4 wt = *(const float4*)(WTbuf + (size_t)b * CN + c0);
    float p[4];
    #pragma unroll
    for (int j = 0; j < 4; ++j) {
        float x = mm[j][0] * wt.x;
        x = fmaf(mm[j][1], wt.y, x);
        x = fmaf(mm[j][2], wt.z, x);
        x = fmaf(mm[j][3], wt.w, x);
        p[j] = x;
    }
    #pragma unroll
    for (int j = 0; j < 4; ++j) {
        p[j] += __shfl_xor(p[j], 1);
        p[j] += __shfl_xor(p[j], 2);
    }
    if (cg == 0) {
        #pragma unroll
        for (int j = 0; j < 4; ++j) psum[w * 64 + vg * 4 + j] = p[j];
    }
    __syncthreads();
    if (t < 128) {
        const int vh = t >> 6, vl = t & 63;
        float s = psum[(0 * 2 + vh) * 64 + vl] + psum[(1 * 2 + vh) * 64 + vl]
                + psum[(2 * 2 + vh) * 64 + vl] + psum[(3 * 2 + vh) * 64 + vl];
        readbuf[(size_t)chain * VD + t] = s;
    }
}

// ---------------- kernel 4: head (256 threads, k-split) ----------------
__global__ __launch_bounds__(256) void k_head(
    const float* __restrict__ readbuf, const int* __restrict__ tgt,
    const float* __restrict__ q_emb,
    const float* __restrict__ rsum_W, const float* __restrict__ rsum_b,
    const float* __restrict__ wsum_W, const float* __restrict__ wsum_b,
    const float* __restrict__ succ_W, const float* __restrict__ succ_b,
    const float* __restrict__ fail_W, const float* __restrict__ fail_b,
    const float* __restrict__ diff_W, const float* __restrict__ diff_b,
    const float* __restrict__ sig, float* __restrict__ out)
{
    __shared__ float xr[256], xw[256];
    __shared__ float part[2][128];
    __shared__ float red_s[6];
    const int t = threadIdx.x;
    const int j = t & 127;
    const int h = t >> 7;
    const int b = blockIdx.x;
    if (h == 0) {
        int tid_ = tgt[b];
        float qv = q_emb[(size_t)tid_ * KD + j];
        xr[j]       = readbuf[(size_t)b * VD + j];
        xr[128 + j] = qv;
        xw[j]       = readbuf[(size_t)(BB + b) * VD + j];
        xw[128 + j] = qv;
    }
    __syncthreads();

    float rs = (h == 0) ? rsum_b[j] : 0.0f;
    float wv = (h == 0) ? wsum_b[j] : 0.0f;
    const float* rw = rsum_W + (size_t)j * 256 + h * 128;
    const float* ww = wsum_W + (size_t)j * 256 + h * 128;
    const float* xrp = xr + h * 128;
    const float* xwp = xw + h * 128;
    #pragma unroll 4
    for (int k = 0; k < 128; ++k) {
        rs = fmaf(rw[k], xrp[k], rs);
        wv = fmaf(ww[k], xwp[k], wv);
    }
    if (h == 1) { part[0][j] = rs; part[1][j] = wv; }
    __syncthreads();
    if (h == 0) {
        rs += part[0][j];
        wv += part[1][j];
        float r_sum = fast_tanh(rs), w_sum = fast_tanh(wv);
        float qv = xr[128 + j];
        float ps = r_sum * succ_W[j];
        float pf = w_sum * fail_W[j];
        float pd = qv    * diff_W[j];
        for (int off = 1; off < 64; off <<= 1) {
            ps += __shfl_xor(ps, off);
            pf += __shfl_xor(pf, off);
            pd += __shfl_xor(pd, off);
        }
        int wid = j >> 6;
        if ((j & 63) == 0) { red_s[wid*3+0] = ps; red_s[wid*3+1] = pf; red_s[wid*3+2] = pd; }
    }
    __syncthreads();
    if (t == 0) {
        float Ps = red_s[0] + red_s[3];
        float Pf = red_s[1] + red_s[4];
        float Pd = red_s[2] + red_s[5];
        float succ = fast_tanh(Ps + succ_b[0]);
        float fail = fast_tanh(Pf + fail_b[0]);
        float diff = fast_tanh(Pd + diff_b[0]);
        out[b] = succ * sig[0] + fail * sig[1] - 2.0f * diff;
    }
}

extern "C" void kernel_launch(void* const* d_in, const int* in_sizes, int n_in,
                              void* d_out, int out_size, void* d_ws, size_t ws_size,
                              hipStream_t stream) {
    const int*   ri      = (const int*)d_in[0];
    const int*   wi      = (const int*)d_in[1];
    const int*   tgt     = (const int*)d_in[2];
    const float* q_emb   = (const float*)d_in[3];
    const float* i_emb   = (const float*)d_in[4];
    const float* key_W   = (const float*)d_in[5];
    const float* erase_W = (const float*)d_in[6];
    const float* erase_b = (const float*)d_in[7];
    const float* add_W   = (const float*)d_in[8];
    const float* add_b   = (const float*)d_in[9];
    const float* rsum_W  = (const float*)d_in[10];
    const float* rsum_b  = (const float*)d_in[11];
    const float* wsum_W  = (const float*)d_in[12];
    const float* wsum_b  = (const float*)d_in[13];
    const float* succ_W  = (const float*)d_in[14];
    const float* succ_b  = (const float*)d_in[15];
    const float* fail_W  = (const float*)d_in[16];
    const float* fail_b  = (const float*)d_in[17];
    const float* diff_W  = (const float*)d_in[18];
    const float* diff_b  = (const float*)d_in[19];
    const float* rmem0   = (const float*)d_in[20];
    const float* wmem0   = (const float*)d_in[21];

    char* ws = (char*)d_ws;
    unsigned int*   EAbuf   = (unsigned int*)(ws + 0);            // 16,777,216 B
    unsigned short* Wbf     = (unsigned short*)(ws + 16777216);   //  4,194,304 B
    float*          WTbuf   = (float*)(ws + 20971520);            //     32,768 B
    float*          readbuf = (float*)(ws + 21004288);            //    131,072 B
    unsigned short* Bfrag   = (unsigned short*)(ws + 21135360);   //     81,920 B
    float*          sig     = (float*)(ws + 21217280);            //          8 B
    float*          out     = (float*)d_out;

    hipLaunchKernelGGL(k_wcnt, dim3(21), dim3(256), 0, stream,
        erase_W, add_W, key_W, Bfrag, ri, wi, sig);
    hipLaunchKernelGGL(k_mfma, dim3(1028), dim3(256), 0, stream,
        ri, wi, tgt, q_emb, i_emb, erase_b, add_b, Bfrag,
        EAbuf, Wbf, WTbuf);
    hipLaunchKernelGGL(k_scan, dim3(256), dim3(512), 0, stream,
        EAbuf, Wbf, WTbuf, rmem0, wmem0, readbuf);
    hipLaunchKernelGGL(k_head, dim3(128), dim3(256), 0, stream,
        readbuf, tgt, q_emb, rsum_W, rsum_b, wsum_W, wsum_b,
        succ_W, succ_b, fail_W, fail_b, diff_W, diff_b, sig, out);
}

// Round 9
// 50.583 us; speedup vs baseline: 1.3584x; 1.1438x over previous
//
#include <hip/hip_runtime.h>
#include <hip/hip_bf16.h>

#define BB 128      // batch
#define SS 128      // seq len
#define VD 128      // VALUE_DIM
#define CN 64       // CONCEPT_NUM
#define KD 128      // KEY_DIM
#define QN 10000

typedef __attribute__((ext_vector_type(8))) short bf16x8;
typedef __attribute__((ext_vector_type(4))) float f32x4;

__device__ __forceinline__ float bflo(unsigned int u) { return __uint_as_float(u << 16); }
__device__ __forceinline__ float bfhi(unsigned int u) { return __uint_as_float(u & 0xffff0000u); }
__device__ __forceinline__ unsigned short f2bf(float f) {
    unsigned int x = __float_as_uint(f);
    return (unsigned short)((x + 0x7fffu + ((x >> 16) & 1u)) >> 16);
}
__device__ __forceinline__ unsigned int pk2(float lo, float hi) {
    return (unsigned int)f2bf(lo) | ((unsigned int)f2bf(hi) << 16);
}
__device__ __forceinline__ float fast_tanh(float x) {
    float e = __expf(2.0f * x);
    return 1.0f - 2.0f / (e + 1.0f);
}
__device__ __forceinline__ float fast_sig(float x) {
    return 1.0f / (1.0f + __expf(-x));
}

// ---------------- kernel 1: weight pack (blocks 0..19) + counts (block 20) ----------------
__global__ __launch_bounds__(256) void k_wcnt(
    const float* __restrict__ erase_W, const float* __restrict__ add_W,
    const float* __restrict__ key_W, unsigned short* __restrict__ Bfrag,
    const int* __restrict__ ri, const int* __restrict__ wi, float* __restrict__ sig)
{
    if (blockIdx.x < 20) {
        const int bid = blockIdx.x * 4 + (threadIdx.x >> 6);   // 0..79
        const int l = threadIdx.x & 63;
        const int n = (bid >> 2) * 16 + (l & 15);
        const int k0 = (bid & 3) * 32 + (l >> 4) * 8;
        const float* src;
        if (n < 128)      src = erase_W + (size_t)n * KD + k0;
        else if (n < 256) src = add_W + (size_t)(n - 128) * KD + k0;
        else              src = key_W + (size_t)(n - 256) * KD + k0;
        float4 fa = ((const float4*)src)[0];
        float4 fb = ((const float4*)src)[1];
        uint4 o = make_uint4(pk2(fa.x, fa.y), pk2(fa.z, fa.w), pk2(fb.x, fb.y), pk2(fb.z, fb.w));
        *(uint4*)(Bfrag + ((size_t)bid * 64 + l) * 8) = o;
    } else {
        __shared__ int sr_s[4], sw_s[4];
        const int t = threadIdx.x;
        const int4* r4 = (const int4*)ri;
        const int4* w4 = (const int4*)wi;
        int sr = 0, sw = 0;
        #pragma unroll 4
        for (int p = 0; p < 16; ++p) {
            int4 a = r4[p * 256 + t];
            int4 b = w4[p * 256 + t];
            sr += (a.x >= 1) + (a.y >= 1) + (a.z >= 1) + (a.w >= 1);
            sw += (b.x >= 1) + (b.y >= 1) + (b.z >= 1) + (b.w >= 1);
        }
        for (int off = 1; off < 64; off <<= 1) { sr += __shfl_xor(sr, off); sw += __shfl_xor(sw, off); }
        int wid = t >> 6;
        if ((t & 63) == 0) { sr_s[wid] = sr; sw_s[wid] = sw; }
        __syncthreads();
        if (t == 0) {
            int SR = sr_s[0]+sr_s[1]+sr_s[2]+sr_s[3];
            int SW = sw_s[0]+sw_s[1]+sw_s[2]+sw_s[3];
            sig[0] = 1.0f / (1.0f + __expf(-(float)SR));
            sig[1] = 1.0f / (1.0f + __expf(-(float)SW));
        }
    }
}

// ---------------- kernel 2: fused per-chain {gather -> MFMA E/A/W -> softmax -> scan -> read} ----------------
// grid 256 = chain (m*BB + b); block 512 = 8 waves.
__global__ __launch_bounds__(512, 2) void k_chain(
    const int* __restrict__ ri, const int* __restrict__ wi, const int* __restrict__ tgt,
    const float* __restrict__ q_emb, const float* __restrict__ i_emb,
    const float* __restrict__ key_W,
    const float* __restrict__ erase_b, const float* __restrict__ add_b,
    const unsigned short* __restrict__ Bfrag,
    const float* __restrict__ rmem0, const float* __restrict__ wmem0,
    float* __restrict__ readbuf)
{
    __shared__ __align__(16) unsigned int lds_ea[SS * VD];    // 64 KB: {e,a} bf16 pair per u32
    __shared__ __align__(16) char xab[32 * 1024];             // 32 KB: Xq, then Xi (bf16, swizzled)
    __shared__ __align__(16) float logits[SS * 68];           // 34816 B
    __shared__ __align__(16) unsigned short lds_w[SS * CN];   // 16 KB: W bf16
    __shared__ float q_t[KD];
    __shared__ float logit_t[CN];
    __shared__ float wt_lds[CN];
    __shared__ int qid_s[SS], ir_s[SS];
    __shared__ float psum[8 * 64];

    const int t = threadIdx.x;
    const int lane = t & 63;
    const int w = t >> 6;
    const int chain = blockIdx.x;
    const int m = chain >> 7;
    const int b = chain & 127;

    // ---- P0: ids + target q row ----
    if (t < SS) {
        int inter = (m == 0 ? ri : wi)[b * SS + t];
        ir_s[t] = inter;
        qid_s[t] = (inter > QN) ? inter - QN : inter;
        q_t[t] = q_emb[(size_t)tgt[b] * KD + t];
    }
    __syncthreads();

    // ---- P1: stage Xq (bf16 swizzled) + target-logit partial dots (f32) ----
    {
        const int r0 = t >> 3, o = t & 7;
        #pragma unroll
        for (int h = 0; h < 2; ++h) {
            const int r = r0 + h * 64;
            const float* src = q_emb + (size_t)qid_s[r] * KD + o * 16;
            float4 f0 = ((const float4*)src)[0];
            float4 f1 = ((const float4*)src)[1];
            float4 f2 = ((const float4*)src)[2];
            float4 f3 = ((const float4*)src)[3];
            const int bb = r * 256 + o * 32;
            const int sw = (r & 7) << 4;
            *(uint4*)(xab + (bb ^ sw))        = make_uint4(pk2(f0.x,f0.y), pk2(f0.z,f0.w), pk2(f1.x,f1.y), pk2(f1.z,f1.w));
            *(uint4*)(xab + ((bb + 16) ^ sw)) = make_uint4(pk2(f2.x,f2.y), pk2(f2.z,f2.w), pk2(f3.x,f3.y), pk2(f3.z,f3.w));
        }
        const int c = t >> 3, oct = t & 7;
        const float* kw = key_W + (size_t)c * KD + oct * 16;
        float s = 0.f;
        #pragma unroll
        for (int i = 0; i < 16; ++i) s = fmaf(kw[i], q_t[oct * 16 + i], s);
        s += __shfl_xor(s, 1); s += __shfl_xor(s, 2); s += __shfl_xor(s, 4);
        if (oct == 0) logit_t[c] = s;
    }
    __syncthreads();

    const int rowl = lane & 15;
    const int kb16 = (lane >> 4) * 16;
    const int rb4 = (lane >> 4) * 4;

    // ---- P2: W-logits MFMA (wave w -> rows w*16..+15, all 4 n-tiles); wave 0 also: target softmax ----
    {
        if (w == 0) {
            float x = logit_t[lane];
            float mx = x;
            #pragma unroll
            for (int off = 1; off < 64; off <<= 1) mx = fmaxf(mx, __shfl_xor(mx, off));
            float e = __expf(x - mx);
            float ssum = e;
            #pragma unroll
            for (int off = 1; off < 64; off <<= 1) ssum += __shfl_xor(ssum, off);
            wt_lds[lane] = e / ssum;
        }
        bf16x8 afQ[4];
        const int row = w * 16 + rowl;
        #pragma unroll
        for (int kt = 0; kt < 4; ++kt)
            afQ[kt] = *(const bf16x8*)(xab + ((row * 256 + kt * 64 + kb16) ^ ((row & 7) << 4)));
        #pragma unroll
        for (int nt = 0; nt < 4; ++nt) {
            f32x4 acc = {0.f,0.f,0.f,0.f};
            #pragma unroll
            for (int kt = 0; kt < 4; ++kt) {
                bf16x8 bf = *(const bf16x8*)(Bfrag + ((size_t)((16 + nt) * 4 + kt) * 64 + lane) * 8);
                acc = __builtin_amdgcn_mfma_f32_16x16x32_bf16(afQ[kt], bf, acc, 0, 0, 0);
            }
            #pragma unroll
            for (int rr = 0; rr < 4; ++rr)
                logits[(w * 16 + rb4 + rr) * 68 + nt * 16 + rowl] = acc[rr];
        }
    }
    __syncthreads();

    // ---- P3: stage Xi (overwrites xab) + softmax-W rows -> lds_w bf16 ----
    {
        const int r0 = t >> 3, o = t & 7;
        uint4 xi[2][2];
        #pragma unroll
        for (int h = 0; h < 2; ++h) {
            const int r = r0 + h * 64;
            const float* src = i_emb + (size_t)ir_s[r] * KD + o * 16;
            float4 f0 = ((const float4*)src)[0];
            float4 f1 = ((const float4*)src)[1];
            float4 f2 = ((const float4*)src)[2];
            float4 f3 = ((const float4*)src)[3];
            xi[h][0] = make_uint4(pk2(f0.x,f0.y), pk2(f0.z,f0.w), pk2(f1.x,f1.y), pk2(f1.z,f1.w));
            xi[h][1] = make_uint4(pk2(f2.x,f2.y), pk2(f2.z,f2.w), pk2(f3.x,f3.y), pk2(f3.z,f3.w));
        }

        // softmax over this row's 64 logits: 4 threads/row, 16 cols each
        const int rr = t >> 2, q4 = t & 3;
        const float* L = logits + rr * 68 + q4 * 16;
        float4 va = ((const float4*)L)[0];
        float4 vb = ((const float4*)L)[1];
        float4 vc = ((const float4*)L)[2];
        float4 vd = ((const float4*)L)[3];
        float mx = fmaxf(fmaxf(fmaxf(va.x, va.y), fmaxf(va.z, va.w)),
                         fmaxf(fmaxf(vb.x, vb.y), fmaxf(vb.z, vb.w)));
        mx = fmaxf(mx, fmaxf(fmaxf(fmaxf(vc.x, vc.y), fmaxf(vc.z, vc.w)),
                             fmaxf(fmaxf(vd.x, vd.y), fmaxf(vd.z, vd.w))));
        mx = fmaxf(mx, __shfl_xor(mx, 1));
        mx = fmaxf(mx, __shfl_xor(mx, 2));
        float ex[16];
        ex[0] = __expf(va.x - mx); ex[1] = __expf(va.y - mx); ex[2] = __expf(va.z - mx); ex[3] = __expf(va.w - mx);
        ex[4] = __expf(vb.x - mx); ex[5] = __expf(vb.y - mx); ex[6] = __expf(vb.z - mx); ex[7] = __expf(vb.w - mx);
        ex[8] = __expf(vc.x - mx); ex[9] = __expf(vc.y - mx); ex[10] = __expf(vc.z - mx); ex[11] = __expf(vc.w - mx);
        ex[12] = __expf(vd.x - mx); ex[13] = __expf(vd.y - mx); ex[14] = __expf(vd.z - mx); ex[15] = __expf(vd.w - mx);
        float s = 0.f;
        #pragma unroll
        for (int i = 0; i < 16; ++i) s += ex[i];
        s += __shfl_xor(s, 1);
        s += __shfl_xor(s, 2);
        float inv = 1.0f / s;
        uint4 o0 = make_uint4(pk2(ex[0]*inv, ex[1]*inv), pk2(ex[2]*inv, ex[3]*inv),
                              pk2(ex[4]*inv, ex[5]*inv), pk2(ex[6]*inv, ex[7]*inv));
        uint4 o1 = make_uint4(pk2(ex[8]*inv, ex[9]*inv), pk2(ex[10]*inv, ex[11]*inv),
                              pk2(ex[12]*inv, ex[13]*inv), pk2(ex[14]*inv, ex[15]*inv));
        *(uint4*)(lds_w + rr * CN + q4 * 16)     = o0;
        *(uint4*)(lds_w + rr * CN + q4 * 16 + 8) = o1;

        // now store Xi into xab (Xq is dead after P2's barrier)
        #pragma unroll
        for (int h = 0; h < 2; ++h) {
            const int r = r0 + h * 64;
            const int bb = r * 256 + o * 32;
            const int sw = (r & 7) << 4;
            *(uint4*)(xab + (bb ^ sw))        = xi[h][0];
            *(uint4*)(xab + ((bb + 16) ^ sw)) = xi[h][1];
        }
    }
    __syncthreads();

    // ---- P4: E/A MFMA (wave w -> rows w*16..+15, 8 col-tile pairs) -> lds_ea packed {e,a} ----
    {
        bf16x8 afI[4];
        const int row = w * 16 + rowl;
        #pragma unroll
        for (int kt = 0; kt < 4; ++kt)
            afI[kt] = *(const bf16x8*)(xab + ((row * 256 + kt * 64 + kb16) ^ ((row & 7) << 4)));
        #pragma unroll
        for (int ci = 0; ci < 8; ++ci) {
            f32x4 ae = {0.f,0.f,0.f,0.f}, aa = {0.f,0.f,0.f,0.f};
            #pragma unroll
            for (int kt = 0; kt < 4; ++kt) {
                bf16x8 be = *(const bf16x8*)(Bfrag + ((size_t)(ci * 4 + kt) * 64 + lane) * 8);
                bf16x8 ba = *(const bf16x8*)(Bfrag + ((size_t)((8 + ci) * 4 + kt) * 64 + lane) * 8);
                ae = __builtin_amdgcn_mfma_f32_16x16x32_bf16(afI[kt], be, ae, 0, 0, 0);
                aa = __builtin_amdgcn_mfma_f32_16x16x32_bf16(afI[kt], ba, aa, 0, 0, 0);
            }
            const int cc = ci * 16 + rowl;
            const float bvE = erase_b[cc];
            const float bvA = add_b[cc];
            #pragma unroll
            for (int rr = 0; rr < 4; ++rr) {
                float e = fast_sig(ae[rr] + bvE);
                float a = fast_tanh(aa[rr] + bvA);
                lds_ea[(w * 16 + rb4 + rr) * VD + cc] = pk2(e, a);
            }
        }
    }

    // init memory state while EA writes drain to barrier
    const int vhalf = w & 1;
    const int cq = w >> 1;
    const int vg = lane >> 2;
    const int cg = lane & 3;
    const int v0 = vhalf * 64 + vg * 4;
    const int c0 = cq * 16 + cg * 4;
    const float* minit = (m == 0) ? rmem0 : wmem0;
    float mm[4][4];
    #pragma unroll
    for (int j = 0; j < 4; ++j) {
        float4 mi = *(const float4*)(minit + (v0 + j) * CN + c0);
        mm[j][0] = mi.x; mm[j][1] = mi.y; mm[j][2] = mi.z; mm[j][3] = mi.w;
    }
    __syncthreads();

    // ---- P5: the scan (R8 structure: 4v x 4c register tile, all-LDS) ----
    for (int so = 0; so < 16; ++so) {
        #pragma unroll
        for (int kk = 0; kk < 8; ++kk) {
            const int s = so * 8 + kk;
            uint4 ea = *(const uint4*)(lds_ea + s * VD + v0);        // ds_read_b128
            uint2 wu = *(const uint2*)(lds_w + s * CN + c0);         // ds_read_b64
            float e[4] = { bflo(ea.x), bflo(ea.y), bflo(ea.z), bflo(ea.w) };
            float a[4] = { bfhi(ea.x), bfhi(ea.y), bfhi(ea.z), bfhi(ea.w) };
            float wv[4] = { bflo(wu.x), bfhi(wu.x), bflo(wu.y), bfhi(wu.y) };
            #pragma unroll
            for (int j = 0; j < 4; ++j) {
                #pragma unroll
                for (int k = 0; k < 4; ++k) {
                    float g = fmaf(-e[j], mm[j][k], a[j]);   // a - e*m
                    mm[j][k] = fmaf(wv[k], g, mm[j][k]);     // m + w*(a - e*m)
                }
            }
        }
    }

    // ---- P6: read epilogue with in-block f32 WT ----
    float4 wt = *(const float4*)(wt_lds + c0);
    float p[4];
    #pragma unroll
    for (int j = 0; j < 4; ++j) {
        float x = mm[j][0] * wt.x;
        x = fmaf(mm[j][1], wt.y, x);
        x = fmaf(mm[j][2], wt.z, x);
        x = fmaf(mm[j][3], wt.w, x);
        p[j] = x;
    }
    #pragma unroll
    for (int j = 0; j < 4; ++j) {
        p[j] += __shfl_xor(p[j], 1);
        p[j] += __shfl_xor(p[j], 2);
    }
    if (cg == 0) {
        #pragma unroll
        for (int j = 0; j < 4; ++j) psum[w * 64 + vg * 4 + j] = p[j];
    }
    __syncthreads();
    if (t < 128) {
        const int vh = t >> 6, vl = t & 63;
        float s = psum[(0 * 2 + vh) * 64 + vl] + psum[(1 * 2 + vh) * 64 + vl]
                + psum[(2 * 2 + vh) * 64 + vl] + psum[(3 * 2 + vh) * 64 + vl];
        readbuf[(size_t)chain * VD + t] = s;
    }
}

// ---------------- kernel 3: head (256 threads, k-split) ----------------
__global__ __launch_bounds__(256) void k_head(
    const float* __restrict__ readbuf, const int* __restrict__ tgt,
    const float* __restrict__ q_emb,
    const float* __restrict__ rsum_W, const float* __restrict__ rsum_b,
    const float* __restrict__ wsum_W, const float* __restrict__ wsum_b,
    const float* __restrict__ succ_W, const float* __restrict__ succ_b,
    const float* __restrict__ fail_W, const float* __restrict__ fail_b,
    const float* __restrict__ diff_W, const float* __restrict__ diff_b,
    const float* __restrict__ sig, float* __restrict__ out)
{
    __shared__ float xr[256], xw[256];
    __shared__ float part[2][128];
    __shared__ float red_s[6];
    const int t = threadIdx.x;
    const int j = t & 127;
    const int h = t >> 7;
    const int b = blockIdx.x;
    if (h == 0) {
        int tid_ = tgt[b];
        float qv = q_emb[(size_t)tid_ * KD + j];
        xr[j]       = readbuf[(size_t)b * VD + j];
        xr[128 + j] = qv;
        xw[j]       = readbuf[(size_t)(BB + b) * VD + j];
        xw[128 + j] = qv;
    }
    __syncthreads();

    float rs = (h == 0) ? rsum_b[j] : 0.0f;
    float wv = (h == 0) ? wsum_b[j] : 0.0f;
    const float* rw = rsum_W + (size_t)j * 256 + h * 128;
    const float* ww = wsum_W + (size_t)j * 256 + h * 128;
    const float* xrp = xr + h * 128;
    const float* xwp = xw + h * 128;
    #pragma unroll 4
    for (int k = 0; k < 128; ++k) {
        rs = fmaf(rw[k], xrp[k], rs);
        wv = fmaf(ww[k], xwp[k], wv);
    }
    if (h == 1) { part[0][j] = rs; part[1][j] = wv; }
    __syncthreads();
    if (h == 0) {
        rs += part[0][j];
        wv += part[1][j];
        float r_sum = fast_tanh(rs), w_sum = fast_tanh(wv);
        float qv = xr[128 + j];
        float ps = r_sum * succ_W[j];
        float pf = w_sum * fail_W[j];
        float pd = qv    * diff_W[j];
        for (int off = 1; off < 64; off <<= 1) {
            ps += __shfl_xor(ps, off);
            pf += __shfl_xor(pf, off);
            pd += __shfl_xor(pd, off);
        }
        int wid = j >> 6;
        if ((j & 63) == 0) { red_s[wid*3+0] = ps; red_s[wid*3+1] = pf; red_s[wid*3+2] = pd; }
    }
    __syncthreads();
    if (t == 0) {
        float Ps = red_s[0] + red_s[3];
        float Pf = red_s[1] + red_s[4];
        float Pd = red_s[2] + red_s[5];
        float succ = fast_tanh(Ps + succ_b[0]);
        float fail = fast_tanh(Pf + fail_b[0]);
        float diff = fast_tanh(Pd + diff_b[0]);
        out[b] = succ * sig[0] + fail * sig[1] - 2.0f * diff;
    }
}

extern "C" void kernel_launch(void* const* d_in, const int* in_sizes, int n_in,
                              void* d_out, int out_size, void* d_ws, size_t ws_size,
                              hipStream_t stream) {
    const int*   ri      = (const int*)d_in[0];
    const int*   wi      = (const int*)d_in[1];
    const int*   tgt     = (const int*)d_in[2];
    const float* q_emb   = (const float*)d_in[3];
    const float* i_emb   = (const float*)d_in[4];
    const float* key_W   = (const float*)d_in[5];
    const float* erase_W = (const float*)d_in[6];
    const float* erase_b = (const float*)d_in[7];
    const float* add_W   = (const float*)d_in[8];
    const float* add_b   = (const float*)d_in[9];
    const float* rsum_W  = (const float*)d_in[10];
    const float* rsum_b  = (const float*)d_in[11];
    const float* wsum_W  = (const float*)d_in[12];
    const float* wsum_b  = (const float*)d_in[13];
    const float* succ_W  = (const float*)d_in[14];
    const float* succ_b  = (const float*)d_in[15];
    const float* fail_W  = (const float*)d_in[16];
    const float* fail_b  = (const float*)d_in[17];
    const float* diff_W  = (const float*)d_in[18];
    const float* diff_b  = (const float*)d_in[19];
    const float* rmem0   = (const float*)d_in[20];
    const float* wmem0   = (const float*)d_in[21];

    char* ws = (char*)d_ws;
    float*          readbuf = (float*)(ws + 0);                   // 131,072 B
    unsigned short* Bfrag   = (unsigned short*)(ws + 131072);     //  81,920 B
    float*          sig     = (float*)(ws + 212992);              //       8 B
    float*          out     = (float*)d_out;

    hipLaunchKernelGGL(k_wcnt, dim3(21), dim3(256), 0, stream,
        erase_W, add_W, key_W, Bfrag, ri, wi, sig);
    hipLaunchKernelGGL(k_chain, dim3(256), dim3(512), 0, stream,
        ri, wi, tgt, q_emb, i_emb, key_W, erase_b, add_b, Bfrag,
        rmem0, wmem0, readbuf);
    hipLaunchKernelGGL(k_head, dim3(128), dim3(256), 0, stream,
        readbuf, tgt, q_emb, rsum_W, rsum_b, wsum_W, wsum_b,
        succ_W, succ_b, fail_W, fail_b, diff_W, diff_b, sig, out);
}